// Round 5
// baseline (129.585 us; speedup 1.0000x reference)
//
#include <hip/hip_runtime.h>

// Problem constants
#define NROWS 8192   // 4 * 2048
#define DIM   512
#define KSLAB (NROWS * 64)          // 524288 B per 64B k-slab (K-major layout)
#define NPAIR 528                   // 32*33/2 (G,g) panel pairs
#define NBLK  (NPAIR * 4)           // 2112 blocks = 8 * 264 (XCD-bijective)
#define NACC  64                    // accumulator slots (contention spread)

typedef __attribute__((ext_vector_type(16))) float f32x16;
typedef __attribute__((ext_vector_type(8)))  int   i32x8;

// Software fp32 -> OCP e4m3fn, round-to-nearest-even (r7/r8-verified).
__device__ __forceinline__ unsigned char f2e4m3(float x) {
    unsigned ux = __float_as_uint(x);
    unsigned s  = (ux >> 24) & 0x80u;
    float a = __uint_as_float(ux & 0x7FFFFFFFu);     // |x|, finite for our data
    a = fminf(a, 448.0f);                            // clamp to max finite
    unsigned ua = __float_as_uint(a);
    int eb = (int)(ua >> 23);                        // biased exponent
    if (eb < 121) eb = 121;                          // denormal region: step 2^-9
    float step  = __uint_as_float((unsigned)(eb - 3) << 23);    // 2^(eb-130)
    float istep = __uint_as_float((unsigned)(257 - eb) << 23);  // 2^(130-eb), exact
    float q = rintf(a * istep) * step;               // RNE on e4m3 grid
    q = fminf(q, 448.0f);
    if (q < 0.001953125f)                            // below min denormal 2^-9 -> 0
        return (unsigned char)s;
    unsigned uq = __float_as_uint(q);
    int eq = (int)(uq >> 23) - 127;
    unsigned byte;
    if (eq < -6) byte = (unsigned)(q * 512.0f);      // denormal: d*2^-9, d in 1..7
    else         byte = (unsigned)((eq + 7) << 3) | ((uq >> 20) & 7u);
    return (unsigned char)(s | byte);
}

// Kernel 1: fp32 row norms + fp32->fp8 conversion.
// r13: Xq is K-SLAB-MAJOR and LINEAR (no swizzle — LDS is gone in kernel 2):
// byte (r, k) lives at Xq[(k>>6)*KSLAB + r*64 + (k&63)]. A GEMM fragment
// read (32 consecutive rows x 64B of one slab) is then fully CONTIGUOUS —
// perfectly coalesced and free of the 512B-stride pattern all prior rounds
// shared. One wave per row; lane's 8B chunk -> slab lane>>3, offset
// row*64 + (lane&7)*8 (8 lanes cover each 64B line).
__global__ __launch_bounds__(256) void norm_convert_kernel(
    const float* __restrict__ X, unsigned char* __restrict__ Xq,
    float* __restrict__ norms, float* __restrict__ acc)
{
    const int tid  = threadIdx.x;
    const int lane = tid & 63;
    const int w    = tid >> 6;
    const int row  = blockIdx.x * 4 + w;

    if (blockIdx.x == 0 && tid < NACC + 1) acc[tid] = 0.0f;  // +1: done-counter

    const float* xr = X + (size_t)row * DIM + lane * 8;
    float4 v0 = *(const float4*)xr;
    float4 v1 = *(const float4*)(xr + 4);

    float s = 0.0f;
    s = fmaf(v0.x, v0.x, s); s = fmaf(v0.y, v0.y, s);
    s = fmaf(v0.z, v0.z, s); s = fmaf(v0.w, v0.w, s);
    s = fmaf(v1.x, v1.x, s); s = fmaf(v1.y, v1.y, s);
    s = fmaf(v1.z, v1.z, s); s = fmaf(v1.w, v1.w, s);

    union { unsigned char b[8]; uint2 v; } pk;
    pk.b[0] = f2e4m3(v0.x); pk.b[1] = f2e4m3(v0.y);
    pk.b[2] = f2e4m3(v0.z); pk.b[3] = f2e4m3(v0.w);
    pk.b[4] = f2e4m3(v1.x); pk.b[5] = f2e4m3(v1.y);
    pk.b[6] = f2e4m3(v1.z); pk.b[7] = f2e4m3(v1.w);

    *(uint2*)(Xq + (size_t)(lane >> 3) * KSLAB + (size_t)row * 64
              + (lane & 7) * 8) = pk.v;

    #pragma unroll
    for (int off = 32; off > 0; off >>= 1) s += __shfl_down(s, off, 64);
    if (lane == 0) norms[row] = s;
}

// Kernel 2: register-direct X·X^T (MX fp8 32x32x64, unit scales) + fused
// sqrt/exp/sum epilogue + fused last-block finalize.
//
// r13 ABLATION/REWRITE (r4 post-mortem: three different LDS-staged
// schedules all ~47-50us; wall tracks blocks/CU, i.e. latency-bound with a
// schedule-insensitive critical path -> remove the staging apparatus
// entirely): X·X^T's A- and B-fragments are BOTH rows of X in the identical
// MFMA fragment layout (lane=row lane&31, 32 k-bytes at (lane>>5)*32), so
// each wave loads frags DIRECTLY global->VGPR. No __shared__ staging, no
// barriers, no global_load_lds, no inline vmcnt — plain loads the compiler
// pipelines (m131-m140: compiler scheduling is only defeated at the
// barrier/DMA path). Two-bank manual double-buffer, all indices static
// (rule #20).
//   - wave = one independent 64x64 tile: 2x2 frags, 64 acc VGPR; ~64KB
//     global reads/wave, 2KB contiguous per frag load (K-major layout).
//   - block = (bi, bj=4g..4g+3): 4 waves share the A-panel via L1 (4KB/
//     step); consecutive blocks (s=0..3 of a pair) share B-panels via L2.
//     Whole Xq = 4MB = one XCD's L2 -> L2-resident after warm-up; expected
//     regime: L2-BW bound (~528MB / 34.5TB/s ~ 15.5us floor).
//   - upper-tri at 64 granularity: wgt 2 off-diag / 1 diag / 0 for bj<bi
//     (diag-group overlap waves, 2.3% waste; keeps all waves uniform for
//     the block reduction).
//   - XCD swizzle bijective: 2112 = 8*264.
// NO device-scope fences (r3: fence = per-XCD L2 flush, +40us).
__global__ __launch_bounds__(256, 3) void pair_loss_gemm_kernel(
    const unsigned char* __restrict__ Xq, const float* __restrict__ norms,
    float* __restrict__ acc, float* __restrict__ out)
{
    __shared__ float wsum[4];
    __shared__ int lastflag;

    // XCD-aware remap (2112 = 8*264, bijective), then (G,g) pair decode
    const int bid = (blockIdx.x & 7) * 264 + (blockIdx.x >> 3);
    int t = bid >> 2, G = 0;
    while (t >= (32 - G)) { t -= (32 - G); G++; }
    const int g = G + t;

    const int tid  = threadIdx.x;
    const int lane = tid & 63;
    const int w    = tid >> 6;          // 0..3

    const int bi = 4 * G + (bid & 3);   // A-tile (64 rows), shared by block
    const int bj = 4 * g + w;           // B-tile, one per wave
    const int rowA = bi * 64;
    const int rowB = bj * 64;

    const int rl = lane & 31;
    const int qh = lane >> 5;
    // frag base: lane reads row (base+rl), bytes qh*32..+32 of each 64B slab
    const unsigned char* pA = Xq + (size_t)(rowA + rl) * 64 + qh * 32;
    const unsigned char* pB = Xq + (size_t)(rowB + rl) * 64 + qh * 32;

    f32x16 accv[2][2];
    #pragma unroll
    for (int a = 0; a < 2; a++)
        #pragma unroll
        for (int b = 0; b < 2; b++)
            #pragma unroll
            for (int r = 0; r < 16; r++) accv[a][b][r] = 0.0f;

    union frag { uint4 u[2]; i32x8 v; };

#define LOADF(dst, base, off) do {                                       \
        (dst).u[0] = *(const uint4*)((base) + (off));                    \
        (dst).u[1] = *(const uint4*)((base) + (off) + 16);               \
    } while (0)

#define MFMA4(A0, A1, B0, B1) do {                                       \
        accv[0][0] = __builtin_amdgcn_mfma_scale_f32_32x32x64_f8f6f4(    \
            (A0).v, (B0).v, accv[0][0], 0, 0, 0, 0x7F7F7F7F, 0, 0x7F7F7F7F); \
        accv[0][1] = __builtin_amdgcn_mfma_scale_f32_32x32x64_f8f6f4(    \
            (A0).v, (B1).v, accv[0][1], 0, 0, 0, 0x7F7F7F7F, 0, 0x7F7F7F7F); \
        accv[1][0] = __builtin_amdgcn_mfma_scale_f32_32x32x64_f8f6f4(    \
            (A1).v, (B0).v, accv[1][0], 0, 0, 0, 0x7F7F7F7F, 0, 0x7F7F7F7F); \
        accv[1][1] = __builtin_amdgcn_mfma_scale_f32_32x32x64_f8f6f4(    \
            (A1).v, (B1).v, accv[1][1], 0, 0, 0, 0x7F7F7F7F, 0, 0x7F7F7F7F); \
    } while (0)

    // two-bank software pipeline over the 8 k-slabs (all indices static)
    frag a0e, a1e, b0e, b1e;            // even bank
    frag a0o, a1o, b0o, b1o;            // odd bank
    LOADF(a0e, pA, (size_t)0);
    LOADF(a1e, pA, (size_t)2048);
    LOADF(b0e, pB, (size_t)0);
    LOADF(b1e, pB, (size_t)2048);

    #pragma unroll
    for (int kk = 0; kk < 4; kk++) {
        const size_t k1 = (size_t)(2 * kk + 1) * KSLAB;
        LOADF(a0o, pA, k1);
        LOADF(a1o, pA, k1 + 2048);
        LOADF(b0o, pB, k1);
        LOADF(b1o, pB, k1 + 2048);
        MFMA4(a0e, a1e, b0e, b1e);

        if (kk < 3) {
            const size_t k2 = (size_t)(2 * kk + 2) * KSLAB;
            LOADF(a0e, pA, k2);
            LOADF(a1e, pA, k2 + 2048);
            LOADF(b0e, pB, k2);
            LOADF(b1e, pB, k2 + 2048);
        }
        MFMA4(a0o, a1o, b0o, b1o);
    }
#undef MFMA4
#undef LOADF

    // epilogue: term = exp(-0.1*sqrt(max(ni+nj-2*dot, 0))); diag -> 1
    // 32x32 C/D: col = lane&31, row = (reg&3) + 8*(reg>>2) + 4*(lane>>5)
    const float wgt = (bj < bi) ? 0.0f : ((bj == bi) ? 1.0f : 2.0f);
    const int cl = lane & 31;
    const int rh = qh * 4;
    float lsum = 0.0f;
    #pragma unroll
    for (int a = 0; a < 2; a++) {
        const int gia = rowA + a * 32;
        float ni[16];
        #pragma unroll
        for (int r = 0; r < 16; r++)
            ni[r] = norms[gia + (r & 3) + 8 * (r >> 2) + rh];
        #pragma unroll
        for (int b = 0; b < 2; b++) {
            const int gj = rowB + b * 32 + cl;
            const float nj = norms[gj];
            #pragma unroll
            for (int r = 0; r < 16; r++) {
                const int gi = gia + (r & 3) + 8 * (r >> 2) + rh;
                float sq = fmaf(-2.0f, accv[a][b][r], ni[r] + nj);
                sq = fmaxf(sq, 0.0f);
                float term = __expf(-0.1f * sqrtf(sq));
                if (gi == gj) term = 1.0f;
                lsum += term;
            }
        }
    }
    lsum *= wgt;
    #pragma unroll
    for (int off = 32; off > 0; off >>= 1) lsum += __shfl_down(lsum, off, 64);
    if (lane == 0) wsum[w] = lsum;
    __syncthreads();

    // fused finalize (r2/r4-verified): last block sums the NACC slots.
    // Ordering WITHOUT a device fence: done-counter atomic issued only after
    // this block's acc-RMW returned (asm keeps value live; in-order issue).
    if (tid == 0) {
        float bsum = wsum[0] + wsum[1] + wsum[2] + wsum[3];
        float old = atomicAdd(&acc[bid & (NACC - 1)], bsum);
        asm volatile("" :: "v"(old));
        unsigned prev = atomicAdd((unsigned int*)(acc + NACC), 1u);
        lastflag = (prev == NBLK - 1) ? 1 : 0;
    }
    __syncthreads();
    if (lastflag && tid < 64) {
        float v = atomicAdd(&acc[tid], 0.0f);    // coherent read (device atomic)
        #pragma unroll
        for (int off = 32; off > 0; off >>= 1) v += __shfl_down(v, off, 64);
        if (tid == 0) {
            const float inv = 1.0f / ((float)NROWS * (float)NROWS); // 2^-26
            float loss = v * inv * 0.1f;
            out[0] = loss;
            out[1] = 0.5f * loss;
        }
    }
}

extern "C" void kernel_launch(void* const* d_in, const int* in_sizes, int n_in,
                              void* d_out, int out_size, void* d_ws, size_t ws_size,
                              hipStream_t stream)
{
    const float* X = (const float*)d_in[0];
    float* out = (float*)d_out;

    char* ws = (char*)d_ws;
    float*         acc   = (float*)ws;                   // NACC slots + counter
    float*         norms = (float*)(ws + 1024);          // 8192 fp32 (32 KB)
    unsigned char* Xq    = (unsigned char*)(ws + 1024 + 32768); // fp8 X, 4 MB

    norm_convert_kernel<<<NROWS / 4, 256, 0, stream>>>(X, Xq, norms, acc);
    pair_loss_gemm_kernel<<<NBLK, 256, 0, stream>>>(Xq, norms, acc, out);
}

// Round 7
// 111.159 us; speedup vs baseline: 1.1658x; 1.1658x over previous
//
#include <hip/hip_runtime.h>

// Problem constants
#define NROWS 8192   // 4 * 2048
#define DIM   512
#define NT    64                    // 8192 / 128 tiles per side
#define NTRI  (NT * (NT + 1) / 2)   // 2080 upper-triangular tile blocks
#define NACC  64                    // accumulator slots (contention spread)

using f32x4 = __attribute__((ext_vector_type(4))) float;

// Software fp32 -> OCP e4m3fn, round-to-nearest-even (r7/r8-verified).
__device__ __forceinline__ unsigned char f2e4m3(float x) {
    unsigned ux = __float_as_uint(x);
    unsigned s  = (ux >> 24) & 0x80u;
    float a = __uint_as_float(ux & 0x7FFFFFFFu);     // |x|, finite for our data
    a = fminf(a, 448.0f);                            // clamp to max finite
    unsigned ua = __float_as_uint(a);
    int eb = (int)(ua >> 23);                        // biased exponent
    if (eb < 121) eb = 121;                          // denormal region: step 2^-9
    float step  = __uint_as_float((unsigned)(eb - 3) << 23);    // 2^(eb-130)
    float istep = __uint_as_float((unsigned)(257 - eb) << 23);  // 2^(130-eb), exact
    float q = rintf(a * istep) * step;               // RNE on e4m3 grid
    q = fminf(q, 448.0f);
    if (q < 0.001953125f)                            // below min denormal 2^-9 -> 0
        return (unsigned char)s;
    unsigned uq = __float_as_uint(q);
    int eq = (int)(uq >> 23) - 127;
    unsigned byte;
    if (eq < -6) byte = (unsigned)(q * 512.0f);      // denormal: d*2^-9, d in 1..7
    else         byte = (unsigned)((eq + 7) << 3) | ((uq >> 20) & 7u);
    return (unsigned char)(s | byte);
}

// Kernel 1: fp32 row norms + fp32->fp8 conversion into a pre-swizzled global
// layout for BK=64 tiles (r0-verified): within each 64B k-slab of row r, 8B
// chunk c is stored at position c ^ (r&7). GEMM staging stays a straight
// linear copy and frag reads are <=2-way in LDS (free, m136).
__global__ __launch_bounds__(256) void norm_convert_kernel(
    const float* __restrict__ X, unsigned char* __restrict__ Xq,
    float* __restrict__ norms, float* __restrict__ acc)
{
    const int tid  = threadIdx.x;
    const int lane = tid & 63;
    const int w    = tid >> 6;
    const int row  = blockIdx.x * 4 + w;

    if (blockIdx.x == 0 && tid < NACC + 1) acc[tid] = 0.0f;  // +1: done-counter

    const float* xr = X + (size_t)row * DIM + lane * 8;
    float4 v0 = *(const float4*)xr;
    float4 v1 = *(const float4*)(xr + 4);

    float s = 0.0f;
    s = fmaf(v0.x, v0.x, s); s = fmaf(v0.y, v0.y, s);
    s = fmaf(v0.z, v0.z, s); s = fmaf(v0.w, v0.w, s);
    s = fmaf(v1.x, v1.x, s); s = fmaf(v1.y, v1.y, s);
    s = fmaf(v1.z, v1.z, s); s = fmaf(v1.w, v1.w, s);

    union { unsigned char b[8]; uint2 v; } pk;
    pk.b[0] = f2e4m3(v0.x); pk.b[1] = f2e4m3(v0.y);
    pk.b[2] = f2e4m3(v0.z); pk.b[3] = f2e4m3(v0.w);
    pk.b[4] = f2e4m3(v1.x); pk.b[5] = f2e4m3(v1.y);
    pk.b[6] = f2e4m3(v1.z); pk.b[7] = f2e4m3(v1.w);

    const int slab = lane >> 3;                      // 64B slab index (0..7)
    const int cpos = (lane & 7) ^ (row & 7);         // swizzled 8B position
    *(uint2*)(Xq + (size_t)row * DIM + slab * 64 + cpos * 8) = pk.v;

    #pragma unroll
    for (int off = 32; off > 0; off >>= 1) s += __shfl_down(s, off, 64);
    if (lane == 0) norms[row] = s;
}

// Kernel 2: upper-triangular tiled X·X^T (fp8 e4m3 MFMA) + fused
// sqrt/exp/sum epilogue + fused last-block finalize.
//
// r7-session recovery round: the GEMM body is r0's best-measured kernel
// UNCHANGED (46.6us, absmax 0.0): 128x128 tile/block, 4 waves, 64x64
// quadrant/wave, BK=64 (two 16x16x32 k-steps per iteration), reg-staged
// LDS double-buffer with 1-step register prefetch. Post-r6 ledger: five
// alternative schedules (gload_lds, MX BK=64/128, counted-vmcnt ring,
// register-direct) all landed 48-85us — this structure stands.
// New vs r0: ONLY the r2/r4-verified last-block finalize (removes the
// finalize dispatch boundary).
// NO device-scope fences (r3: agent fence = per-XCD L2 flush, +40us).
// Cooperative launch is NOT usable (r6: silent launch failure, out=0).
__global__ __launch_bounds__(256, 4) void pair_loss_gemm_kernel(
    const unsigned char* __restrict__ Xq, const float* __restrict__ norms,
    float* __restrict__ acc, float* __restrict__ out)
{
    __shared__ __align__(16) char As0[8192];
    __shared__ __align__(16) char As1[8192];
    __shared__ __align__(16) char Bs0[8192];
    __shared__ __align__(16) char Bs1[8192];
    __shared__ float wsum[4];
    __shared__ int lastflag;

    // decode linear block id -> upper-triangular (bi, bj), bi <= bj
    int t = blockIdx.x, bi = 0;
    while (t >= (NT - bi)) { t -= (NT - bi); bi++; }
    const int bj = bi + t;

    const int tid  = threadIdx.x;
    const int lane = tid & 63;
    const int w    = tid >> 6;

    const int rowA = bi * 128;
    const int rowB = bj * 128;

    f32x4 accv[4][4];
    const f32x4 zero = {0.0f, 0.0f, 0.0f, 0.0f};
    #pragma unroll
    for (int a = 0; a < 4; a++)
        #pragma unroll
        for (int b = 0; b < 4; b++) accv[a][b] = zero;

    // staging: thread -> row r0 = tid>>1, 32B half h0 = tid&1 of the 64B slab.
    const int r0 = tid >> 1;
    const int h0 = tid & 1;
    const int wb = r0 * 64 + h0 * 32;            // LDS byte offset
    const unsigned char* gA = Xq + (size_t)(rowA + r0) * DIM + h0 * 32;
    const unsigned char* gB = Xq + (size_t)(rowB + r0) * DIM + h0 * 32;

    // MFMA fp8 frag: lane holds A[m=fr][k=q*8..q*8+7] per k-step, q=lane>>4.
    // Chunk index in the 64B slab: kstep*4+q, at swizzled position ^(fr&7).
    const int fr  = lane & 15;
    const int q   = lane >> 4;
    const int fo0 = fr * 64 + ((q ^ (fr & 7)) * 8);
    const int wr  = (w & 1) * 64;
    const int wc  = (w >> 1) * 64;

    // prologue: stage slab 0 through registers
    {
        uint4 pa0 = *(const uint4*)gA;
        uint4 pa1 = *(const uint4*)(gA + 16);
        uint4 pb0 = *(const uint4*)gB;
        uint4 pb1 = *(const uint4*)(gB + 16);
        *(uint4*)(As0 + wb)      = pa0;
        *(uint4*)(As0 + wb + 16) = pa1;
        *(uint4*)(Bs0 + wb)      = pb0;
        *(uint4*)(Bs0 + wb + 16) = pb1;
    }
    __syncthreads();

    char* curA = As0; char* nxtA = As1;
    char* curB = Bs0; char* nxtB = Bs1;

    #pragma unroll 1
    for (int k = 0; k < 8; k++) {
        // prefetch next 64B K-slab into registers (in flight across 2 k-steps)
        uint4 pa0, pa1, pb0, pb1;
        const bool more = (k < 7);
        if (more) {
            const int k0 = (k + 1) * 64;
            pa0 = *(const uint4*)(gA + k0);
            pa1 = *(const uint4*)(gA + k0 + 16);
            pb0 = *(const uint4*)(gB + k0);
            pb1 = *(const uint4*)(gB + k0 + 16);
        }

        #pragma unroll
        for (int s = 0; s < 2; s++) {
            const int fo = fo0 ^ (s << 5);
            long af[4], bf[4];
            #pragma unroll
            for (int a = 0; a < 4; a++)
                af[a] = *(const long*)(curA + (wr + a * 16) * 64 + fo);
            #pragma unroll
            for (int b = 0; b < 4; b++)
                bf[b] = *(const long*)(curB + (wc + b * 16) * 64 + fo);
            #pragma unroll
            for (int a = 0; a < 4; a++)
                #pragma unroll
                for (int b = 0; b < 4; b++)
                    accv[a][b] = __builtin_amdgcn_mfma_f32_16x16x32_fp8_fp8(
                        af[a], bf[b], accv[a][b], 0, 0, 0);
        }

        if (more) {
            *(uint4*)(nxtA + wb)      = pa0;  // vmcnt wait lands here
            *(uint4*)(nxtA + wb + 16) = pa1;
            *(uint4*)(nxtB + wb)      = pb0;
            *(uint4*)(nxtB + wb + 16) = pb1;
            __syncthreads();
            char* tA = curA; curA = nxtA; nxtA = tA;
            char* tB = curB; curB = nxtB; nxtB = tB;
        }
    }

    // epilogue: term = exp(-0.1*sqrt(max(ni+nj-2*dot, 0))); diag -> 1
    // C/D layout: col = lane&15, row = (lane>>4)*4 + reg (dtype-independent)
    const float wgt = (bi == bj) ? 1.0f : 2.0f;
    float lsum = 0.0f;
    #pragma unroll
    for (int a = 0; a < 4; a++) {
        const int gi0 = rowA + wr + a * 16 + (lane >> 4) * 4;
        #pragma unroll
        for (int b = 0; b < 4; b++) {
            const int gj = rowB + wc + b * 16 + (lane & 15);
            const float nj = norms[gj];
            #pragma unroll
            for (int r = 0; r < 4; r++) {
                const int gi = gi0 + r;
                float sq = fmaf(-2.0f, accv[a][b][r], norms[gi] + nj);
                sq = fmaxf(sq, 0.0f);
                float term = __expf(-0.1f * sqrtf(sq));
                if (gi == gj) term = 1.0f;
                lsum += term;
            }
        }
    }
    lsum *= wgt;
    #pragma unroll
    for (int off = 32; off > 0; off >>= 1) lsum += __shfl_down(lsum, off, 64);
    if (lane == 0) wsum[w] = lsum;
    __syncthreads();

    // fused finalize (r2/r4-verified, absmax 0 twice): last block to
    // complete sums the NACC slots. Ordering WITHOUT a device fence: the
    // done-counter atomic is issued only after this block's acc-RMW has
    // returned (asm keeps the value live -> s_waitcnt vmcnt before it;
    // wave issue is in-order).
    if (tid == 0) {
        float bsum = wsum[0] + wsum[1] + wsum[2] + wsum[3];
        float old = atomicAdd(&acc[blockIdx.x & (NACC - 1)], bsum);
        asm volatile("" :: "v"(old));
        unsigned prev = atomicAdd((unsigned int*)(acc + NACC), 1u);
        lastflag = (prev == NTRI - 1) ? 1 : 0;
    }
    __syncthreads();
    if (lastflag && tid < 64) {
        float v = atomicAdd(&acc[tid], 0.0f);    // coherent read (device atomic)
        #pragma unroll
        for (int off = 32; off > 0; off >>= 1) v += __shfl_down(v, off, 64);
        if (tid == 0) {
            const float inv = 1.0f / ((float)NROWS * (float)NROWS); // 2^-26 exact
            float loss = v * inv * 0.1f;
            out[0] = loss;
            out[1] = 0.5f * loss;
        }
    }
}

extern "C" void kernel_launch(void* const* d_in, const int* in_sizes, int n_in,
                              void* d_out, int out_size, void* d_ws, size_t ws_size,
                              hipStream_t stream)
{
    const float* X = (const float*)d_in[0];
    float* out = (float*)d_out;

    char* ws = (char*)d_ws;
    float*         acc   = (float*)ws;                   // NACC slots + counter
    float*         norms = (float*)(ws + 1024);          // 8192 fp32 (32 KB)
    unsigned char* Xq    = (unsigned char*)(ws + 1024 + 32768); // fp8 X, 4 MB

    norm_convert_kernel<<<NROWS / 4, 256, 0, stream>>>(X, Xq, norms, acc);
    pair_loss_gemm_kernel<<<NTRI, 256, 0, stream>>>(Xq, norms, acc, out);
}